// Round 9
// baseline (115.450 us; speedup 1.0000x reference)
//
#include <hip/hip_runtime.h>
#include <hip/hip_bf16.h>

// Problem constants (fixed by reference): N=10000, D=128, E=640000.
#define NB    256      // sort blocks; each owns E/NB edges
#define EPB   2500     // edges per sort block
#define NPAD  10240    // scan width: 256 threads * 40 nodes
#define NPT   40       // nodes per thread in scan
#define NGEMM 625      // gemm role blocks (10000/16)
#define LCAP  1024     // per-wave src-list capacity (max degree ~110 for this input)

typedef __bf16 bf16_8 __attribute__((ext_vector_type(8)));
typedef float f32_4 __attribute__((ext_vector_type(4)));
typedef float f32_8 __attribute__((ext_vector_type(8)));

// ---------------------------------------------------------------------------
// k_fused: blockIdx-split roles (identical to R7 best).
//  blocks [0,625):      z = x @ W^T  (bf16 MFMA 16x16x32, inline f32->bf16)
//  blocks [625,625+256): counting-sort 2500 edges by dst (LDS only).
// Outputs: bins[b][0..2499] (src ushort grouped by dst, coalesced store),
//          combo[b][n] = (count<<16)|excl_off  (coalesced uint4 stores).
// ---------------------------------------------------------------------------
__global__ void __launch_bounds__(256) k_fused(
    const float* __restrict__ x, const float* __restrict__ W,
    const int* __restrict__ ei, int E,
    __hip_bfloat16* __restrict__ zb, unsigned short* __restrict__ bins,
    unsigned int* __restrict__ combo) {
  __shared__ int h[NPAD / 2];               // 20.5 KB packed counts -> cursors
  __shared__ unsigned short sorted[EPB];    // 5 KB
  __shared__ int wsum[4];

  if (blockIdx.x < NGEMM) {
    // ---- zgemm role: einsum('nd,od->no') => B[k][n] = W[n][k], read W rows.
    // A frag: A[m=lane&15][k=quad*8+j]; C/D: col=lane&15, row=quad*4+reg (m89).
    int rowbase = blockIdx.x * 16;
    int wid = threadIdx.x >> 6;
    int lane = threadIdx.x & 63;
    int m16 = lane & 15;
    int quad = lane >> 4;

    union { bf16_8 v; __hip_bfloat16 h8[8]; } ac[4];
    const float* arow = x + (size_t)(rowbase + m16) * 128 + quad * 8;
#pragma unroll
    for (int kk = 0; kk < 4; ++kk) {
      f32_8 af = *(const f32_8*)(arow + kk * 32);
#pragma unroll
      for (int j = 0; j < 8; ++j) ac[kk].h8[j] = __float2bfloat16(af[j]);
    }
#pragma unroll
    for (int ct = 0; ct < 2; ++ct) {
      int colbase = wid * 32 + ct * 16;
      const float* brow = W + (size_t)(colbase + m16) * 128 + quad * 8;
      f32_4 c = {0.f, 0.f, 0.f, 0.f};
#pragma unroll
      for (int kk = 0; kk < 4; ++kk) {
        f32_8 bf = *(const f32_8*)(brow + kk * 32);
        union { bf16_8 v; __hip_bfloat16 h8[8]; } bc;
#pragma unroll
        for (int j = 0; j < 8; ++j) bc.h8[j] = __float2bfloat16(bf[j]);
        c = __builtin_amdgcn_mfma_f32_16x16x32_bf16(ac[kk].v, bc.v, c, 0, 0, 0);
      }
#pragma unroll
      for (int r = 0; r < 4; ++r) {
        int row = rowbase + quad * 4 + r;
        zb[(size_t)row * 128 + colbase + m16] = __float2bfloat16(c[r]);
      }
    }
    return;
  }

  // ---- sort role ----
  const int b = blockIdx.x - NGEMM;
  const int t = threadIdx.x;
  const int4* src4 = (const int4*)(ei) + b * (EPB / 4);
  const int4* dst4 = (const int4*)(ei + E) + b * (EPB / 4);

  for (int i = t; i < NPAD / 2; i += 256) h[i] = 0;
  __syncthreads();

  // Pass A: histogram (packed-pair LDS atomics)
  for (int i = t; i < EPB / 4; i += 256) {
    int4 d = dst4[i];
    atomicAdd(&h[d.x >> 1], 1 << ((d.x & 1) * 16));
    atomicAdd(&h[d.y >> 1], 1 << ((d.y & 1) * 16));
    atomicAdd(&h[d.z >> 1], 1 << ((d.z & 1) * 16));
    atomicAdd(&h[d.w >> 1], 1 << ((d.w & 1) * 16));
  }
  __syncthreads();

  // Pass B: block-wide exclusive scan; emit packed cursors + combo row.
  int raw[NPT];
  const int lo = t * NPT;  // even
  int sum = 0;
#pragma unroll
  for (int j = 0; j < NPT; j += 2) {
    int pair = h[(lo + j) >> 1];
    raw[j] = pair & 0xFFFF;
    raw[j + 1] = (pair >> 16) & 0xFFFF;
    sum += raw[j] + raw[j + 1];
  }
  int incl = sum;
#pragma unroll
  for (int off = 1; off < 64; off <<= 1) {
    int v = __shfl_up(incl, off);
    if ((t & 63) >= off) incl += v;
  }
  if ((t & 63) == 63) wsum[t >> 6] = incl;
  __syncthreads();
  int wb = 0;
  for (int w = 0; w < (t >> 6); ++w) wb += wsum[w];
  int run = wb + incl - sum;  // block-wide exclusive prefix for this range

  unsigned int cpack[NPT];
#pragma unroll
  for (int j = 0; j < NPT; j += 2) {
    int r0 = run; run += raw[j];
    int r1 = run; run += raw[j + 1];
    h[(lo + j) >> 1] = (r1 << 16) | r0;  // packed cursors for Pass C
    cpack[j]     = ((unsigned)raw[j] << 16) | (unsigned)r0;
    cpack[j + 1] = ((unsigned)raw[j + 1] << 16) | (unsigned)r1;
  }
  __syncthreads();

  // combo row write: fully coalesced (10 x uint4 per thread)
  unsigned int* crow = combo + (size_t)b * NPAD + lo;
#pragma unroll
  for (int j = 0; j < NPT; j += 4)
    *(uint4*)(crow + j) = make_uint4(cpack[j], cpack[j+1], cpack[j+2], cpack[j+3]);

  // Pass C: rank via packed-pair atomic rtn, scatter into LDS sorted list
  for (int i = t; i < EPB / 4; i += 256) {
    int4 s4 = src4[i];
    int4 d4 = dst4[i];
    int ss[4] = {s4.x, s4.y, s4.z, s4.w};
    int dd[4] = {d4.x, d4.y, d4.z, d4.w};
#pragma unroll
    for (int u = 0; u < 4; ++u) {
      int n = dd[u];
      int sh = (n & 1) * 16;
      int pos = (atomicAdd(&h[n >> 1], 1 << sh) >> sh) & 0xFFFF;
      sorted[pos] = (unsigned short)ss[u];
    }
  }
  __syncthreads();

  // stream out coalesced (2500 ushort = 1250 uint)
  unsigned int* outb = (unsigned int*)(bins + (size_t)b * EPB);
  const unsigned int* s32 = (const unsigned int*)sorted;
  for (int i = t; i < EPB / 2; i += 256) outb[i] = s32[i];
}

// ---------------------------------------------------------------------------
// k_agg: R7 structure + runtime `reps` dose knob around the gather loop.
// reps=2 re-executes the gather exactly; normalization divides by reps*deg.
// Runtime trip count prevents compiler CSE -> the delta vs R7 measures the
// gather's true cost.
// ---------------------------------------------------------------------------
__global__ void __launch_bounds__(256) k_agg(
    const unsigned int* __restrict__ combo, const unsigned short* __restrict__ bins,
    const __hip_bfloat16* __restrict__ zb, const float* __restrict__ bias,
    float* __restrict__ out, int N, int reps) {
  __shared__ unsigned int trans[4][256];      // 4 KB
  __shared__ unsigned short list[4][LCAP];    // 8 KB
  __shared__ int cursor[4];

  const int t = threadIdx.x;
  const int wid = t >> 6;
  const int lane = t & 63;
  const int n0 = blockIdx.x * 4;

  if (t < 4) cursor[t] = 0;
  uint4 cm = *(const uint4*)(combo + (size_t)t * NPAD + n0);
  trans[0][t] = cm.x; trans[1][t] = cm.y; trans[2][t] = cm.z; trans[3][t] = cm.w;
  __syncthreads();

  const int n = n0 + wid;
  uint4 cc = *(const uint4*)&trans[wid][4 * lane];
  int cs[4] = {(int)(cc.x >> 16), (int)(cc.y >> 16), (int)(cc.z >> 16), (int)(cc.w >> 16)};
  int os[4] = {(int)(cc.x & 0xFFFF), (int)(cc.y & 0xFFFF), (int)(cc.z & 0xFFFF), (int)(cc.w & 0xFFFF)};
  int tot = cs[0] + cs[1] + cs[2] + cs[3];

  int p = atomicAdd(&cursor[wid], tot);  // LDS cursor: order-free slot reserve

  {
    int q = p;
#pragma unroll
    for (int k = 0; k < 4; ++k) {
      int c = cs[k];
      const unsigned short* bk = bins + (size_t)(4 * lane + k) * EPB + os[k];
      unsigned short s0 = 0, s1 = 0, s2 = 0;
      if (c > 0) s0 = bk[0];           // independent guarded loads
      if (c > 1) s1 = bk[1];
      if (c > 2) s2 = bk[2];
      if (c > 0 && q < LCAP) list[wid][q] = s0;
      if (c > 1 && q + 1 < LCAP) list[wid][q + 1] = s1;
      if (c > 2 && q + 2 < LCAP) list[wid][q + 2] = s2;
      for (int j = 3; j < c; ++j)      // rare tail (P ~ 1e-4 per segment)
        if (q + j < LCAP) list[wid][q + j] = bk[j];
      q += c;
    }
  }
  __syncthreads();

  const int m = cursor[wid];  // true degree of node n
  const int g = lane >> 4;    // row-group
  const int sub = lane & 15;  // 16-B chunk of 256-B row
  int mm = m < LCAP ? m : LCAP;

  float acc[8] = {0.f, 0.f, 0.f, 0.f, 0.f, 0.f, 0.f, 0.f};
  for (int rep = 0; rep < reps; ++rep) {     // dose knob (runtime, no CSE)
    for (int e = 0; e < mm; e += 32) {
#pragma unroll
      for (int u = 0; u < 8; ++u) {
        int idx = e + u * 4 + g;
        if (idx < mm) {
          int s = list[wid][idx];
          bf16_8 v = *(const bf16_8*)(zb + (size_t)s * 128 + sub * 8);
#pragma unroll
          for (int k = 0; k < 8; ++k) acc[k] += (float)v[k];
        }
      }
    }
  }
#pragma unroll
  for (int k = 0; k < 8; ++k) {
    acc[k] += __shfl_xor(acc[k], 16);
    acc[k] += __shfl_xor(acc[k], 32);
  }

  if (g == 0 && n < N) {
    float inv = 1.f / (float)(reps * (m > 0 ? m : 1));
    bf16_8 zn = *(const bf16_8*)(zb + (size_t)n * 128 + sub * 8);
    f32_8 bv = *(const f32_8*)(bias + sub * 8);
    float r[8];
#pragma unroll
    for (int k = 0; k < 8; ++k) {
      float v = acc[k] * inv + (float)zn[k] + bv[k];
      r[k] = v > 0.f ? v : 0.f;
    }
    float* o = out + (size_t)n * 128 + sub * 8;
    *(float4*)(o)     = make_float4(r[0], r[1], r[2], r[3]);
    *(float4*)(o + 4) = make_float4(r[4], r[5], r[6], r[7]);
  }
}

// ---------------------------------------------------------------------------
extern "C" void kernel_launch(void* const* d_in, const int* in_sizes, int n_in,
                              void* d_out, int out_size, void* d_ws, size_t ws_size,
                              hipStream_t stream) {
  const float* x = (const float*)d_in[0];
  const int* ei = (const int*)d_in[1];
  const float* W = (const float*)d_in[2];
  const float* b = (const float*)d_in[3];
  float* out = (float*)d_out;

  const int N = in_sizes[0] / 128;  // 10000
  const int E = in_sizes[1] / 2;    // 640000 (= NB * EPB)

  char* ws = (char*)d_ws;
  size_t off = 0;
  auto carve = [&](size_t bytes) {
    void* p = ws + off;
    off = (off + bytes + 255) & ~(size_t)255;
    return p;
  };
  __hip_bfloat16* zb = (__hip_bfloat16*)carve((size_t)N * 128 * 2);     // 2.56 MB
  unsigned short* bins = (unsigned short*)carve((size_t)NB * EPB * 2);  // 1.28 MB
  unsigned int* combo = (unsigned int*)carve((size_t)NB * NPAD * 4);    // 10.5 MB

  // 1) fused: z = x@W^T (blocks 0..624) || per-block counting sort (625..880)
  k_fused<<<NGEMM + NB, 256, 0, stream>>>(x, W, ei, E, zb, bins, combo);
  // 2) gather (x2 dose) + segment-sum + /(reps*deg) + z[n] + bias + relu
  k_agg<<<N / 4, 256, 0, stream>>>(combo, bins, zb, b, out, N, 2);
}

// Round 11
// 103.091 us; speedup vs baseline: 1.1199x; 1.1199x over previous
//
#include <hip/hip_runtime.h>
#include <hip/hip_bf16.h>
#include <hip/hip_fp8.h>

// Problem constants (fixed by reference): N=10000, D=128, E=640000.
#define NB    256      // sort blocks; each owns E/NB edges
#define EPB   2500     // edges per sort block
#define NPAD  10240    // scan width: 256 threads * 40 nodes
#define NPT   40       // nodes per thread in scan
#define NGEMM 625      // gemm role blocks (10000/16)
#define LCAP  1024     // per-wave src-list capacity (max degree ~110 for this input)

typedef __bf16 bf16_8 __attribute__((ext_vector_type(8)));
typedef float f32_2 __attribute__((ext_vector_type(2)));
typedef float f32_4 __attribute__((ext_vector_type(4)));
typedef float f32_8 __attribute__((ext_vector_type(8)));

// ---------------------------------------------------------------------------
// k_fused: blockIdx-split roles (R7 structure + fp8 z shadow copy).
//  blocks [0,625):      z = x @ W^T (bf16 MFMA); write z as bf16 AND fp8 e4m3
//  blocks [625,625+256): counting-sort 2500 edges by dst (LDS only).
// Outputs: zb (bf16, self-term), zb8 (fp8, gather rows: 128 B/row),
//          bins[b][0..2499] (src ushort grouped by dst), combo[b][n].
// ---------------------------------------------------------------------------
__global__ void __launch_bounds__(256) k_fused(
    const float* __restrict__ x, const float* __restrict__ W,
    const int* __restrict__ ei, int E,
    __hip_bfloat16* __restrict__ zb, unsigned char* __restrict__ zb8,
    unsigned short* __restrict__ bins, unsigned int* __restrict__ combo) {
  __shared__ int h[NPAD / 2];               // 20.5 KB packed counts -> cursors
  __shared__ unsigned short sorted[EPB];    // 5 KB
  __shared__ int wsum[4];

  if (blockIdx.x < NGEMM) {
    // ---- zgemm role: einsum('nd,od->no') => B[k][n] = W[n][k], read W rows.
    // A frag: A[m=lane&15][k=quad*8+j]; C/D: col=lane&15, row=quad*4+reg (m89).
    int rowbase = blockIdx.x * 16;
    int wid = threadIdx.x >> 6;
    int lane = threadIdx.x & 63;
    int m16 = lane & 15;
    int quad = lane >> 4;

    union { bf16_8 v; __hip_bfloat16 h8[8]; } ac[4];
    const float* arow = x + (size_t)(rowbase + m16) * 128 + quad * 8;
#pragma unroll
    for (int kk = 0; kk < 4; ++kk) {
      f32_8 af = *(const f32_8*)(arow + kk * 32);
#pragma unroll
      for (int j = 0; j < 8; ++j) ac[kk].h8[j] = __float2bfloat16(af[j]);
    }
#pragma unroll
    for (int ct = 0; ct < 2; ++ct) {
      int colbase = wid * 32 + ct * 16;
      const float* brow = W + (size_t)(colbase + m16) * 128 + quad * 8;
      f32_4 c = {0.f, 0.f, 0.f, 0.f};
#pragma unroll
      for (int kk = 0; kk < 4; ++kk) {
        f32_8 bf = *(const f32_8*)(brow + kk * 32);
        union { bf16_8 v; __hip_bfloat16 h8[8]; } bc;
#pragma unroll
        for (int j = 0; j < 8; ++j) bc.h8[j] = __float2bfloat16(bf[j]);
        c = __builtin_amdgcn_mfma_f32_16x16x32_bf16(ac[kk].v, bc.v, c, 0, 0, 0);
      }
#pragma unroll
      for (int r = 0; r < 4; ++r) {
        int row = rowbase + quad * 4 + r;
        zb[(size_t)row * 128 + colbase + m16] = __float2bfloat16(c[r]);
        zb8[(size_t)row * 128 + colbase + m16] = __hip_fp8_e4m3(c[r]).__x;
      }
    }
    return;
  }

  // ---- sort role ----
  const int b = blockIdx.x - NGEMM;
  const int t = threadIdx.x;
  const int4* src4 = (const int4*)(ei) + b * (EPB / 4);
  const int4* dst4 = (const int4*)(ei + E) + b * (EPB / 4);

  for (int i = t; i < NPAD / 2; i += 256) h[i] = 0;
  __syncthreads();

  // Pass A: histogram (packed-pair LDS atomics)
  for (int i = t; i < EPB / 4; i += 256) {
    int4 d = dst4[i];
    atomicAdd(&h[d.x >> 1], 1 << ((d.x & 1) * 16));
    atomicAdd(&h[d.y >> 1], 1 << ((d.y & 1) * 16));
    atomicAdd(&h[d.z >> 1], 1 << ((d.z & 1) * 16));
    atomicAdd(&h[d.w >> 1], 1 << ((d.w & 1) * 16));
  }
  __syncthreads();

  // Pass B: block-wide exclusive scan; emit packed cursors + combo row.
  int raw[NPT];
  const int lo = t * NPT;  // even
  int sum = 0;
#pragma unroll
  for (int j = 0; j < NPT; j += 2) {
    int pair = h[(lo + j) >> 1];
    raw[j] = pair & 0xFFFF;
    raw[j + 1] = (pair >> 16) & 0xFFFF;
    sum += raw[j] + raw[j + 1];
  }
  int incl = sum;
#pragma unroll
  for (int off = 1; off < 64; off <<= 1) {
    int v = __shfl_up(incl, off);
    if ((t & 63) >= off) incl += v;
  }
  if ((t & 63) == 63) wsum[t >> 6] = incl;
  __syncthreads();
  int wb = 0;
  for (int w = 0; w < (t >> 6); ++w) wb += wsum[w];
  int run = wb + incl - sum;  // block-wide exclusive prefix for this range

  unsigned int cpack[NPT];
#pragma unroll
  for (int j = 0; j < NPT; j += 2) {
    int r0 = run; run += raw[j];
    int r1 = run; run += raw[j + 1];
    h[(lo + j) >> 1] = (r1 << 16) | r0;  // packed cursors for Pass C
    cpack[j]     = ((unsigned)raw[j] << 16) | (unsigned)r0;
    cpack[j + 1] = ((unsigned)raw[j + 1] << 16) | (unsigned)r1;
  }
  __syncthreads();

  // combo row write: fully coalesced (10 x uint4 per thread)
  unsigned int* crow = combo + (size_t)b * NPAD + lo;
#pragma unroll
  for (int j = 0; j < NPT; j += 4)
    *(uint4*)(crow + j) = make_uint4(cpack[j], cpack[j+1], cpack[j+2], cpack[j+3]);

  // Pass C: rank via packed-pair atomic rtn, scatter into LDS sorted list
  for (int i = t; i < EPB / 4; i += 256) {
    int4 s4 = src4[i];
    int4 d4 = dst4[i];
    int ss[4] = {s4.x, s4.y, s4.z, s4.w};
    int dd[4] = {d4.x, d4.y, d4.z, d4.w};
#pragma unroll
    for (int u = 0; u < 4; ++u) {
      int n = dd[u];
      int sh = (n & 1) * 16;
      int pos = (atomicAdd(&h[n >> 1], 1 << sh) >> sh) & 0xFFFF;
      sorted[pos] = (unsigned short)ss[u];
    }
  }
  __syncthreads();

  // stream out coalesced (2500 ushort = 1250 uint)
  unsigned int* outb = (unsigned int*)(bins + (size_t)b * EPB);
  const unsigned int* s32 = (const unsigned int*)sorted;
  for (int i = t; i < EPB / 2; i += 256) outb[i] = s32[i];
}

// ---------------------------------------------------------------------------
// k_agg: R7 structure; gather reads fp8 rows (128 B/row, half the L2 traffic),
// decodes with HW packed cvt (v_cvt_pk_f32_fp8: 2 floats/inst, literal word
// selector). Self-term z[n] stays bf16.
// ---------------------------------------------------------------------------
__global__ void __launch_bounds__(256) k_agg(
    const unsigned int* __restrict__ combo, const unsigned short* __restrict__ bins,
    const unsigned char* __restrict__ zb8, const __hip_bfloat16* __restrict__ zb,
    const float* __restrict__ bias, float* __restrict__ out, int N) {
  __shared__ unsigned int trans[4][256];      // 4 KB
  __shared__ unsigned short list[4][LCAP];    // 8 KB
  __shared__ int cursor[4];

  const int t = threadIdx.x;
  const int wid = t >> 6;
  const int lane = t & 63;
  const int n0 = blockIdx.x * 4;

  if (t < 4) cursor[t] = 0;
  uint4 cm = *(const uint4*)(combo + (size_t)t * NPAD + n0);
  trans[0][t] = cm.x; trans[1][t] = cm.y; trans[2][t] = cm.z; trans[3][t] = cm.w;
  __syncthreads();

  const int n = n0 + wid;
  uint4 cc = *(const uint4*)&trans[wid][4 * lane];
  int cs[4] = {(int)(cc.x >> 16), (int)(cc.y >> 16), (int)(cc.z >> 16), (int)(cc.w >> 16)};
  int os[4] = {(int)(cc.x & 0xFFFF), (int)(cc.y & 0xFFFF), (int)(cc.z & 0xFFFF), (int)(cc.w & 0xFFFF)};
  int tot = cs[0] + cs[1] + cs[2] + cs[3];

  int p = atomicAdd(&cursor[wid], tot);  // LDS cursor: order-free slot reserve

  {
    int q = p;
#pragma unroll
    for (int k = 0; k < 4; ++k) {
      int c = cs[k];
      const unsigned short* bk = bins + (size_t)(4 * lane + k) * EPB + os[k];
      unsigned short s0 = 0, s1 = 0, s2 = 0;
      if (c > 0) s0 = bk[0];           // independent guarded loads
      if (c > 1) s1 = bk[1];
      if (c > 2) s2 = bk[2];
      if (c > 0 && q < LCAP) list[wid][q] = s0;
      if (c > 1 && q + 1 < LCAP) list[wid][q + 1] = s1;
      if (c > 2 && q + 2 < LCAP) list[wid][q + 2] = s2;
      for (int j = 3; j < c; ++j)      // rare tail (P ~ 1e-4 per segment)
        if (q + j < LCAP) list[wid][q + j] = bk[j];
      q += c;
    }
  }
  __syncthreads();

  const int m = cursor[wid];  // true degree of node n
  const int g = lane >> 4;    // row-group
  const int sub = lane & 15;  // 8-B chunk of the 128-B fp8 row
  int mm = m < LCAP ? m : LCAP;

  const unsigned char* z8base = zb8 + sub * 8;

  float acc[8] = {0.f, 0.f, 0.f, 0.f, 0.f, 0.f, 0.f, 0.f};
  for (int e = 0; e < mm; e += 32) {
    // phase 1: issue up to 8 independent 8-B fp8 row loads
    uint2 v[8];
#pragma unroll
    for (int u = 0; u < 8; ++u) {
      int idx = e + u * 4 + g;
      v[u] = make_uint2(0u, 0u);
      if (idx < mm) {
        int s = list[wid][idx];
        v[u] = *(const uint2*)(z8base + (size_t)s * 128);
      }
    }
    // phase 2: packed HW fp8->f32 decode + accumulate (0x00 decodes to 0.0)
#pragma unroll
    for (int u = 0; u < 8; ++u) {
      f32_2 p01 = __builtin_amdgcn_cvt_pk_f32_fp8((int)v[u].x, false);
      f32_2 p23 = __builtin_amdgcn_cvt_pk_f32_fp8((int)v[u].x, true);
      f32_2 p45 = __builtin_amdgcn_cvt_pk_f32_fp8((int)v[u].y, false);
      f32_2 p67 = __builtin_amdgcn_cvt_pk_f32_fp8((int)v[u].y, true);
      acc[0] += p01[0]; acc[1] += p01[1];
      acc[2] += p23[0]; acc[3] += p23[1];
      acc[4] += p45[0]; acc[5] += p45[1];
      acc[6] += p67[0]; acc[7] += p67[1];
    }
  }
#pragma unroll
  for (int k = 0; k < 8; ++k) {
    acc[k] += __shfl_xor(acc[k], 16);
    acc[k] += __shfl_xor(acc[k], 32);
  }

  if (g == 0 && n < N) {
    float inv = 1.f / (float)(m > 0 ? m : 1);
    bf16_8 zn = *(const bf16_8*)(zb + (size_t)n * 128 + sub * 8);
    f32_8 bv = *(const f32_8*)(bias + sub * 8);
    float r[8];
#pragma unroll
    for (int k = 0; k < 8; ++k) {
      float v2 = acc[k] * inv + (float)zn[k] + bv[k];
      r[k] = v2 > 0.f ? v2 : 0.f;
    }
    float* o = out + (size_t)n * 128 + sub * 8;
    *(float4*)(o)     = make_float4(r[0], r[1], r[2], r[3]);
    *(float4*)(o + 4) = make_float4(r[4], r[5], r[6], r[7]);
  }
}

// ---------------------------------------------------------------------------
extern "C" void kernel_launch(void* const* d_in, const int* in_sizes, int n_in,
                              void* d_out, int out_size, void* d_ws, size_t ws_size,
                              hipStream_t stream) {
  const float* x = (const float*)d_in[0];
  const int* ei = (const int*)d_in[1];
  const float* W = (const float*)d_in[2];
  const float* b = (const float*)d_in[3];
  float* out = (float*)d_out;

  const int N = in_sizes[0] / 128;  // 10000
  const int E = in_sizes[1] / 2;    // 640000 (= NB * EPB)

  char* ws = (char*)d_ws;
  size_t off = 0;
  auto carve = [&](size_t bytes) {
    void* p = ws + off;
    off = (off + bytes + 255) & ~(size_t)255;
    return p;
  };
  __hip_bfloat16* zb = (__hip_bfloat16*)carve((size_t)N * 128 * 2);     // 2.56 MB
  unsigned char* zb8 = (unsigned char*)carve((size_t)N * 128);          // 1.28 MB
  unsigned short* bins = (unsigned short*)carve((size_t)NB * EPB * 2);  // 1.28 MB
  unsigned int* combo = (unsigned int*)carve((size_t)NB * NPAD * 4);    // 10.5 MB

  // 1) fused: z = x@W^T (bf16 + fp8 shadow) || per-block counting sort
  k_fused<<<NGEMM + NB, 256, 0, stream>>>(x, W, ei, E, zb, zb8, bins, combo);
  // 2) fp8 gather + segment-sum + /deg + z[n] + bias + relu
  k_agg<<<N / 4, 256, 0, stream>>>(combo, bins, zb8, zb, b, out, N);
}

// Round 12
// 96.584 us; speedup vs baseline: 1.1953x; 1.0674x over previous
//
#include <hip/hip_runtime.h>
#include <hip/hip_bf16.h>
#include <hip/hip_fp8.h>

// Problem constants (fixed by reference): N=10000, D=128, E=640000.
#define NB    64       // sort blocks; each owns E/NB edges
#define EPB   10000    // edges per sort block
#define NPAD  10240    // scan width: 256 threads * 40 nodes
#define NPT   40       // nodes per thread in scan
#define NGEMM 625      // gemm role blocks (10000/16)
#define LCAP  1024     // per-wave src-list capacity (max degree ~110 for this input)

typedef __bf16 bf16_8 __attribute__((ext_vector_type(8)));
typedef float f32_2 __attribute__((ext_vector_type(2)));
typedef float f32_4 __attribute__((ext_vector_type(4)));
typedef float f32_8 __attribute__((ext_vector_type(8)));

// ---------------------------------------------------------------------------
// k_fused: blockIdx-split roles.
//  blocks [0,625):     z = x @ W^T (bf16 MFMA); write z as bf16 AND fp8 e4m3
//  blocks [625,625+64): counting-sort 10000 edges by dst (LDS only).
// Outputs: zb (bf16 self-term), zb8 (fp8 gather rows, 128 B/row),
//          bins[b][0..9999] (src ushort grouped by dst),
//          combo[b][n] = (count<<16)|excl_off  (2.6 MB total, 4x smaller).
// ---------------------------------------------------------------------------
__global__ void __launch_bounds__(256) k_fused(
    const float* __restrict__ x, const float* __restrict__ W,
    const int* __restrict__ ei, int E,
    __hip_bfloat16* __restrict__ zb, unsigned char* __restrict__ zb8,
    unsigned short* __restrict__ bins, unsigned int* __restrict__ combo) {
  __shared__ int h[NPAD / 2];               // 20.5 KB packed counts -> cursors
  __shared__ unsigned short sorted[EPB];    // 20 KB
  __shared__ int wsum[4];

  if (blockIdx.x < NGEMM) {
    // ---- zgemm role: einsum('nd,od->no') => B[k][n] = W[n][k], read W rows.
    // A frag: A[m=lane&15][k=quad*8+j]; C/D: col=lane&15, row=quad*4+reg (m89).
    int rowbase = blockIdx.x * 16;
    int wid = threadIdx.x >> 6;
    int lane = threadIdx.x & 63;
    int m16 = lane & 15;
    int quad = lane >> 4;

    union { bf16_8 v; __hip_bfloat16 h8[8]; } ac[4];
    const float* arow = x + (size_t)(rowbase + m16) * 128 + quad * 8;
#pragma unroll
    for (int kk = 0; kk < 4; ++kk) {
      f32_8 af = *(const f32_8*)(arow + kk * 32);
#pragma unroll
      for (int j = 0; j < 8; ++j) ac[kk].h8[j] = __float2bfloat16(af[j]);
    }
#pragma unroll
    for (int ct = 0; ct < 2; ++ct) {
      int colbase = wid * 32 + ct * 16;
      const float* brow = W + (size_t)(colbase + m16) * 128 + quad * 8;
      f32_4 c = {0.f, 0.f, 0.f, 0.f};
#pragma unroll
      for (int kk = 0; kk < 4; ++kk) {
        f32_8 bf = *(const f32_8*)(brow + kk * 32);
        union { bf16_8 v; __hip_bfloat16 h8[8]; } bc;
#pragma unroll
        for (int j = 0; j < 8; ++j) bc.h8[j] = __float2bfloat16(bf[j]);
        c = __builtin_amdgcn_mfma_f32_16x16x32_bf16(ac[kk].v, bc.v, c, 0, 0, 0);
      }
#pragma unroll
      for (int r = 0; r < 4; ++r) {
        int row = rowbase + quad * 4 + r;
        zb[(size_t)row * 128 + colbase + m16] = __float2bfloat16(c[r]);
        zb8[(size_t)row * 128 + colbase + m16] = __hip_fp8_e4m3(c[r]).__x;
      }
    }
    return;
  }

  // ---- sort role ----
  const int b = blockIdx.x - NGEMM;
  const int t = threadIdx.x;
  const int4* src4 = (const int4*)(ei) + b * (EPB / 4);
  const int4* dst4 = (const int4*)(ei + E) + b * (EPB / 4);

  for (int i = t; i < NPAD / 2; i += 256) h[i] = 0;
  __syncthreads();

  // Pass A: histogram (packed-pair LDS atomics)
  for (int i = t; i < EPB / 4; i += 256) {
    int4 d = dst4[i];
    atomicAdd(&h[d.x >> 1], 1 << ((d.x & 1) * 16));
    atomicAdd(&h[d.y >> 1], 1 << ((d.y & 1) * 16));
    atomicAdd(&h[d.z >> 1], 1 << ((d.z & 1) * 16));
    atomicAdd(&h[d.w >> 1], 1 << ((d.w & 1) * 16));
  }
  __syncthreads();

  // Pass B: block-wide exclusive scan; emit packed cursors + combo row.
  int raw[NPT];
  const int lo = t * NPT;  // even
  int sum = 0;
#pragma unroll
  for (int j = 0; j < NPT; j += 2) {
    int pair = h[(lo + j) >> 1];
    raw[j] = pair & 0xFFFF;
    raw[j + 1] = (pair >> 16) & 0xFFFF;
    sum += raw[j] + raw[j + 1];
  }
  int incl = sum;
#pragma unroll
  for (int off = 1; off < 64; off <<= 1) {
    int v = __shfl_up(incl, off);
    if ((t & 63) >= off) incl += v;
  }
  if ((t & 63) == 63) wsum[t >> 6] = incl;
  __syncthreads();
  int wb = 0;
  for (int w = 0; w < (t >> 6); ++w) wb += wsum[w];
  int run = wb + incl - sum;  // block-wide exclusive prefix for this range

  unsigned int cpack[NPT];
#pragma unroll
  for (int j = 0; j < NPT; j += 2) {
    int r0 = run; run += raw[j];
    int r1 = run; run += raw[j + 1];
    h[(lo + j) >> 1] = (r1 << 16) | r0;  // packed cursors for Pass C
    cpack[j]     = ((unsigned)raw[j] << 16) | (unsigned)r0;
    cpack[j + 1] = ((unsigned)raw[j + 1] << 16) | (unsigned)r1;
  }
  __syncthreads();

  // combo row write: fully coalesced (10 x uint4 per thread)
  unsigned int* crow = combo + (size_t)b * NPAD + lo;
#pragma unroll
  for (int j = 0; j < NPT; j += 4)
    *(uint4*)(crow + j) = make_uint4(cpack[j], cpack[j+1], cpack[j+2], cpack[j+3]);

  // Pass C: rank via packed-pair atomic rtn, scatter into LDS sorted list
  for (int i = t; i < EPB / 4; i += 256) {
    int4 s4 = src4[i];
    int4 d4 = dst4[i];
    int ss[4] = {s4.x, s4.y, s4.z, s4.w};
    int dd[4] = {d4.x, d4.y, d4.z, d4.w};
#pragma unroll
    for (int u = 0; u < 4; ++u) {
      int n = dd[u];
      int sh = (n & 1) * 16;
      int pos = (atomicAdd(&h[n >> 1], 1 << sh) >> sh) & 0xFFFF;
      sorted[pos] = (unsigned short)ss[u];
    }
  }
  __syncthreads();

  // stream out coalesced (10000 ushort = 5000 uint)
  unsigned int* outb = (unsigned int*)(bins + (size_t)b * EPB);
  const unsigned int* s32 = (const unsigned int*)sorted;
  for (int i = t; i < EPB / 2; i += 256) outb[i] = s32[i];
}

// ---------------------------------------------------------------------------
// k_agg: block = 4 nodes (one per wave). NB=64 => exactly one segment/lane:
//  1. threads 0..63 read ONE uint4 = combo[t][n0..n0+3] (64x16B, 4x L2 reuse)
//     -> LDS transpose.
//  2. lane l owns segment l (avg 1.0 edges): LDS cursor reserve, 3 guarded
//     independent loads (covers 98%), rare tail.
//  3. fp8 row gathers (128 B/row, 8 in flight) + packed HW fp8->f32 decode.
//  4. shfl_xor(16,32) reduce -> /deg + z[n] + bias + relu -> fp32 out.
// ---------------------------------------------------------------------------
__global__ void __launch_bounds__(256) k_agg(
    const unsigned int* __restrict__ combo, const unsigned short* __restrict__ bins,
    const unsigned char* __restrict__ zb8, const __hip_bfloat16* __restrict__ zb,
    const float* __restrict__ bias, float* __restrict__ out, int N) {
  __shared__ unsigned int trans[4][64];       // 1 KB
  __shared__ unsigned short list[4][LCAP];    // 8 KB
  __shared__ int cursor[4];

  const int t = threadIdx.x;
  const int wid = t >> 6;
  const int lane = t & 63;
  const int n0 = blockIdx.x * 4;

  if (t < 4) cursor[t] = 0;
  if (t < 64) {
    uint4 cm = *(const uint4*)(combo + (size_t)t * NPAD + n0);
    trans[0][t] = cm.x; trans[1][t] = cm.y; trans[2][t] = cm.z; trans[3][t] = cm.w;
  }
  __syncthreads();

  const int n = n0 + wid;
  unsigned int cc = trans[wid][lane];
  int c = (int)(cc >> 16);
  int o = (int)(cc & 0xFFFF);

  int p = atomicAdd(&cursor[wid], c);  // LDS cursor: order-free slot reserve

  {
    const unsigned short* bk = bins + (size_t)lane * EPB + o;
    unsigned short s0 = 0, s1 = 0, s2 = 0;
    if (c > 0) s0 = bk[0];             // independent guarded loads
    if (c > 1) s1 = bk[1];
    if (c > 2) s2 = bk[2];
    if (c > 0 && p < LCAP) list[wid][p] = s0;
    if (c > 1 && p + 1 < LCAP) list[wid][p + 1] = s1;
    if (c > 2 && p + 2 < LCAP) list[wid][p + 2] = s2;
    for (int j = 3; j < c; ++j)        // tail: P(c>3 | lambda=1) ~ 2%
      if (p + j < LCAP) list[wid][p + j] = bk[j];
  }
  __syncthreads();

  const int m = cursor[wid];  // true degree of node n
  const int g = lane >> 4;    // row-group
  const int sub = lane & 15;  // 8-B chunk of the 128-B fp8 row
  int mm = m < LCAP ? m : LCAP;

  const unsigned char* z8base = zb8 + sub * 8;

  float acc[8] = {0.f, 0.f, 0.f, 0.f, 0.f, 0.f, 0.f, 0.f};
  for (int e = 0; e < mm; e += 32) {
    // phase 1: issue up to 8 independent 8-B fp8 row loads
    uint2 v[8];
#pragma unroll
    for (int u = 0; u < 8; ++u) {
      int idx = e + u * 4 + g;
      v[u] = make_uint2(0u, 0u);
      if (idx < mm) {
        int s = list[wid][idx];
        v[u] = *(const uint2*)(z8base + (size_t)s * 128);
      }
    }
    // phase 2: packed HW fp8->f32 decode + accumulate (0x00 decodes to 0.0)
#pragma unroll
    for (int u = 0; u < 8; ++u) {
      f32_2 p01 = __builtin_amdgcn_cvt_pk_f32_fp8((int)v[u].x, false);
      f32_2 p23 = __builtin_amdgcn_cvt_pk_f32_fp8((int)v[u].x, true);
      f32_2 p45 = __builtin_amdgcn_cvt_pk_f32_fp8((int)v[u].y, false);
      f32_2 p67 = __builtin_amdgcn_cvt_pk_f32_fp8((int)v[u].y, true);
      acc[0] += p01[0]; acc[1] += p01[1];
      acc[2] += p23[0]; acc[3] += p23[1];
      acc[4] += p45[0]; acc[5] += p45[1];
      acc[6] += p67[0]; acc[7] += p67[1];
    }
  }
#pragma unroll
  for (int k = 0; k < 8; ++k) {
    acc[k] += __shfl_xor(acc[k], 16);
    acc[k] += __shfl_xor(acc[k], 32);
  }

  if (g == 0 && n < N) {
    float inv = 1.f / (float)(m > 0 ? m : 1);
    bf16_8 zn = *(const bf16_8*)(zb + (size_t)n * 128 + sub * 8);
    f32_8 bv = *(const f32_8*)(bias + sub * 8);
    float r[8];
#pragma unroll
    for (int k = 0; k < 8; ++k) {
      float v2 = acc[k] * inv + (float)zn[k] + bv[k];
      r[k] = v2 > 0.f ? v2 : 0.f;
    }
    float* o2 = out + (size_t)n * 128 + sub * 8;
    *(float4*)(o2)     = make_float4(r[0], r[1], r[2], r[3]);
    *(float4*)(o2 + 4) = make_float4(r[4], r[5], r[6], r[7]);
  }
}

// ---------------------------------------------------------------------------
extern "C" void kernel_launch(void* const* d_in, const int* in_sizes, int n_in,
                              void* d_out, int out_size, void* d_ws, size_t ws_size,
                              hipStream_t stream) {
  const float* x = (const float*)d_in[0];
  const int* ei = (const int*)d_in[1];
  const float* W = (const float*)d_in[2];
  const float* b = (const float*)d_in[3];
  float* out = (float*)d_out;

  const int N = in_sizes[0] / 128;  // 10000
  const int E = in_sizes[1] / 2;    // 640000 (= NB * EPB)

  char* ws = (char*)d_ws;
  size_t off = 0;
  auto carve = [&](size_t bytes) {
    void* p = ws + off;
    off = (off + bytes + 255) & ~(size_t)255;
    return p;
  };
  __hip_bfloat16* zb = (__hip_bfloat16*)carve((size_t)N * 128 * 2);     // 2.56 MB
  unsigned char* zb8 = (unsigned char*)carve((size_t)N * 128);          // 1.28 MB
  unsigned short* bins = (unsigned short*)carve((size_t)NB * EPB * 2);  // 1.28 MB
  unsigned int* combo = (unsigned int*)carve((size_t)NB * NPAD * 4);    // 2.62 MB

  // 1) fused: z = x@W^T (bf16 + fp8 shadow) || per-block counting sort
  k_fused<<<NGEMM + NB, 256, 0, stream>>>(x, W, ei, E, zb, zb8, bins, combo);
  // 2) fp8 gather + segment-sum + /deg + z[n] + bias + relu
  k_agg<<<N / 4, 256, 0, stream>>>(combo, bins, zb8, zb, b, out, N);
}